// Round 4
// baseline (1228.847 us; speedup 1.0000x reference)
//
#include <hip/hip_runtime.h>
#include <cstddef>
#include <cstdint>

#define HDIM 256
#define BSEG 4096

typedef __bf16 bf16x8 __attribute__((ext_vector_type(8)));
typedef ushort u16x8 __attribute__((ext_vector_type(8)));
typedef float f32x4 __attribute__((ext_vector_type(4)));

__device__ __forceinline__ float leaky(float x) { return x >= 0.f ? x : 0.1f * x; }

__device__ __forceinline__ float bf2f(ushort u) {
    return __builtin_bit_cast(float, (uint32_t)u << 16);
}
__device__ __forceinline__ ushort f2bf(float f) {  // RNE
    uint32_t x = __builtin_bit_cast(uint32_t, f);
    return (ushort)((x + 0x7fffu + ((x >> 16) & 1u)) >> 16);
}
__device__ __forceinline__ bf16x8 pack8(float4 a, float4 b) {
    u16x8 u;
    u[0] = f2bf(a.x); u[1] = f2bf(a.y); u[2] = f2bf(a.z); u[3] = f2bf(a.w);
    u[4] = f2bf(b.x); u[5] = f2bf(b.y); u[6] = f2bf(b.z); u[7] = f2bf(b.w);
    return __builtin_bit_cast(bf16x8, u);
}

// async global->LDS, 16 bytes per lane
__device__ __forceinline__ void gld16(const ushort* g, ushort* lds) {
    __builtin_amdgcn_global_load_lds(
        (const __attribute__((address_space(1))) uint32_t*)g,
        (__attribute__((address_space(3))) uint32_t*)lds, 16, 0, 0);
}

// ---------- segment bounds (batch arrays sorted) ----------
__global__ void seg_bounds_k(const int* __restrict__ bc, const int* __restrict__ bp,
                             int* __restrict__ sc, int* __restrict__ sp, int n, int nb)
{
    int t = blockIdx.x * blockDim.x + threadIdx.x;
    if (t >= 2 * (nb + 1)) return;
    bool isc = (t <= nb);
    const int* a = isc ? bc : bp;
    int v = isc ? t : t - (nb + 1);
    int lo = 0, hi = n;
    while (lo < hi) { int mid = (lo + hi) >> 1; if (a[mid] < v) lo = mid + 1; else hi = mid; }
    if (isc) sc[t] = lo; else sp[t - (nb + 1)] = lo;
}

// ---------- all 256x256 weight transpose+casts in one launch ----------
__global__ __launch_bounds__(256) void wt_cast_all(
    const float* __restrict__ s0, const float* __restrict__ s1,
    const float* __restrict__ s2, const float* __restrict__ s3,
    const float* __restrict__ s4, const float* __restrict__ s5,
    ushort* __restrict__ d0, ushort* __restrict__ d1, ushort* __restrict__ d2,
    ushort* __restrict__ d3, ushort* __restrict__ d4, ushort* __restrict__ d5)
{
    int m = blockIdx.x >> 8;
    int i = (blockIdx.x & 255) * 256 + threadIdx.x;   // 0..65535
    const float* s = m == 0 ? s0 : m == 1 ? s1 : m == 2 ? s2 : m == 3 ? s3 : m == 4 ? s4 : s5;
    ushort*      d = m == 0 ? d0 : m == 1 ? d1 : m == 2 ? d2 : m == 3 ? d3 : m == 4 ? d4 : d5;
    int r = i >> 8, c = i & 255;
    d[(size_t)c * 256 + r] = f2bf(s[i]);
}

// ---------- W-resident MFMA GEMM: no K-loop barriers ----------
// A:[nrows,256] (fp32 if AFP32 else bf16) row-major, streamed global->VGPR.
// WT:[NOtot,256] bf16 (weights pre-transposed); one 128-col slice staged in LDS.
// 128x128 tile/block, 4 waves 2x2 (64x64 each). Output halves of 256 cols.
// ALPHADOT: half 1 isn't stored; instead dot with w2 -> ppart[inhalf][row].
template<bool LEAKYACT, bool ROWBIAS, bool AFP32, bool ALPHADOT, int YT>
__global__ __launch_bounds__(256) void mgemm_w(
    const void* __restrict__ Av, const ushort* __restrict__ WT,
    const float* __restrict__ bias0, const float* __restrict__ bias1,
    const float* __restrict__ rt0, const float* __restrict__ rt1,
    const int* __restrict__ idx,
    ushort* __restrict__ out0, ushort* __restrict__ out1,
    const float* __restrict__ w2, float* __restrict__ ppart, int nrows)
{
    __shared__ __attribute__((aligned(16))) ushort Ws[128 * 256];   // 64 KB

    const int tid = threadIdx.x;
    const uint nwg = gridDim.x;
    const uint orig = blockIdx.x;
    const uint swz = (orig & 7) * (nwg >> 3) + (orig >> 3);   // XCD-chunked
    const int bx = (int)(swz / YT), by = (int)(swz % YT);
    const int row0 = bx * 128, col0 = by * 128;

    // stage W slice [128 cols][256 k], k-slot XOR-swizzled (pre-swizzled source,
    // linear LDS dest as global_load_lds requires)
    {
        const int scol = tid >> 5;     // 0..7  (== col & 7)
        const int sslot = tid & 31;    // dest 16B slot within 512B row
        #pragma unroll
        for (int i = 0; i < 16; ++i) {
            const int col = i * 8 + scol;
            gld16(WT + (size_t)(col0 + col) * HDIM + ((sslot ^ scol) << 3),
                  &Ws[i * 2048 + tid * 8]);
        }
    }
    __syncthreads();

    const int w = tid >> 6, l = tid & 63;
    const int wr = (w >> 1) * 64, wc = (w & 1) * 64;
    const int lr = l & 15, lt = l >> 4;

    const float*  Af = (const float*)Av;
    const ushort* Ah = (const ushort*)Av;
    size_t arow[4];
    #pragma unroll
    for (int m = 0; m < 4; ++m) arow[m] = (size_t)(row0 + wr + m * 16 + lr) * HDIM;
    int wbase[4];
    #pragma unroll
    for (int n = 0; n < 4; ++n) wbase[n] = (wc + n * 16 + lr) * HDIM;
    const int lxor = lr & 7;

    f32x4 acc[4][4] = {};

    #pragma unroll
    for (int ks = 0; ks < 8; ++ks) {
        const int k0 = ks * 32;
        bf16x8 af[4], bv[4];
        #pragma unroll
        for (int m = 0; m < 4; ++m) {
            if (AFP32) {
                float4 x = *(const float4*)&Af[arow[m] + k0 + lt * 8];
                float4 y = *(const float4*)&Af[arow[m] + k0 + lt * 8 + 4];
                af[m] = pack8(x, y);
            } else {
                af[m] = *(const bf16x8*)&Ah[arow[m] + k0 + lt * 8];
            }
        }
        const int slot = ((k0 >> 3) + lt) ^ lxor;
        #pragma unroll
        for (int n = 0; n < 4; ++n)
            bv[n] = *(const bf16x8*)&Ws[wbase[n] + (slot << 3)];
        #pragma unroll
        for (int m = 0; m < 4; ++m)
            #pragma unroll
            for (int n = 0; n < 4; ++n)
                acc[m][n] = __builtin_amdgcn_mfma_f32_16x16x32_bf16(bv[n], af[m], acc[m][n], 0, 0, 0);
    }

    const int half = (YT == 4) ? (by >> 1) : 0;
    const int inhalf = (YT == 4) ? (by & 1) : by;
    const float* bias = half ? bias1 : bias0;
    const float* rtab = half ? rt1 : rt0;
    ushort* outp = half ? out1 : out0;
    const int oc0 = inhalf * 128 + wc + (lt << 2);

    if (ALPHADOT && half == 1) {
        // hidden = leaky(acc + rtab[idx[row]]); p = dot(hidden_slice, w2_slice)
        #pragma unroll
        for (int m = 0; m < 4; ++m) {
            const int row = row0 + wr + m * 16 + lr;
            const float* rrow = rtab + (size_t)idx[row] * HDIM;
            float p = 0.f;
            #pragma unroll
            for (int n = 0; n < 4; ++n) {
                const int c = oc0 + n * 16;
                float4 r4 = *(const float4*)&rrow[c];
                float4 w4 = *(const float4*)&w2[c];
                float v0 = acc[m][n][0] + r4.x, v1 = acc[m][n][1] + r4.y;
                float v2 = acc[m][n][2] + r4.z, v3 = acc[m][n][3] + r4.w;
                if (LEAKYACT) { v0 = leaky(v0); v1 = leaky(v1); v2 = leaky(v2); v3 = leaky(v3); }
                p += v0 * w4.x + v1 * w4.y + v2 * w4.z + v3 * w4.w;
            }
            p += __shfl_xor(p, 16);
            p += __shfl_xor(p, 32);
            if (lt == 0) ppart[(size_t)inhalf * nrows + row] = p;
        }
    } else {
        #pragma unroll
        for (int m = 0; m < 4; ++m) {
            const int row = row0 + wr + m * 16 + lr;
            const float* rrow = nullptr;
            if (ROWBIAS) rrow = rtab + (size_t)idx[row] * HDIM;
            #pragma unroll
            for (int n = 0; n < 4; ++n) {
                const int c = oc0 + n * 16;
                float v0 = acc[m][n][0], v1 = acc[m][n][1], v2 = acc[m][n][2], v3 = acc[m][n][3];
                if (bias) {
                    float4 b4 = *(const float4*)&bias[c];
                    v0 += b4.x; v1 += b4.y; v2 += b4.z; v3 += b4.w;
                }
                if (ROWBIAS) {
                    float4 r4 = *(const float4*)&rrow[c];
                    v0 += r4.x; v1 += r4.y; v2 += r4.z; v3 += r4.w;
                }
                if (LEAKYACT) { v0 = leaky(v0); v1 = leaky(v1); v2 = leaky(v2); v3 = leaky(v3); }
                ushort4 o; o.x = f2bf(v0); o.y = f2bf(v1); o.z = f2bf(v2); o.w = f2bf(v3);
                *(ushort4*)&outp[(size_t)row * HDIM + c] = o;
            }
        }
    }
}

// ---------- fp32 tiled GEMM (small dual [B,H] GEMMs) ----------
template<bool LEAKYACT, bool ROWBIAS, bool DUAL>
__global__ __launch_bounds__(256) void gemm64(
    const float* __restrict__ A, const float* __restrict__ W,
    const float* __restrict__ A2, const float* __restrict__ W2,
    const float* __restrict__ bias, const float* __restrict__ rowtab,
    const int* __restrict__ idx, float* __restrict__ C, int M)
{
    const int K = HDIM, NO = HDIM;
    __shared__ float As [16][68];
    __shared__ float Bs [16][68];
    __shared__ float As2[16][68];
    __shared__ float Bs2[16][68];

    const int tid = threadIdx.x;
    const int tx = tid & 15, ty = tid >> 4;
    const int row0 = blockIdx.x * 64, col0 = blockIdx.y * 64;

    const int lr = tid >> 2;
    const int lk = (tid & 3) << 2;
    const int bk = tid >> 4;
    const int bj = (tid & 15) << 2;

    float acc[4][4] = {};

    for (int k0 = 0; k0 < K; k0 += 16) {
        float4 a4 = *(const float4*)&A[(size_t)(row0 + lr) * K + k0 + lk];
        As[lk + 0][lr] = a4.x; As[lk + 1][lr] = a4.y;
        As[lk + 2][lr] = a4.z; As[lk + 3][lr] = a4.w;
        *(float4*)&Bs[bk][bj] = *(const float4*)&W[(size_t)(k0 + bk) * NO + col0 + bj];
        if (DUAL) {
            float4 c4 = *(const float4*)&A2[(size_t)(row0 + lr) * K + k0 + lk];
            As2[lk + 0][lr] = c4.x; As2[lk + 1][lr] = c4.y;
            As2[lk + 2][lr] = c4.z; As2[lk + 3][lr] = c4.w;
            *(float4*)&Bs2[bk][bj] = *(const float4*)&W2[(size_t)(k0 + bk) * NO + col0 + bj];
        }
        __syncthreads();
        #pragma unroll
        for (int kk = 0; kk < 16; ++kk) {
            float4 av = *(const float4*)&As[kk][ty << 2];
            float4 bv = *(const float4*)&Bs[kk][tx << 2];
            float a_[4] = {av.x, av.y, av.z, av.w};
            float b_[4] = {bv.x, bv.y, bv.z, bv.w};
            #pragma unroll
            for (int i = 0; i < 4; ++i)
                #pragma unroll
                for (int j = 0; j < 4; ++j)
                    acc[i][j] += a_[i] * b_[j];
            if (DUAL) {
                float4 av2 = *(const float4*)&As2[kk][ty << 2];
                float4 bv2 = *(const float4*)&Bs2[kk][tx << 2];
                float c_[4] = {av2.x, av2.y, av2.z, av2.w};
                float d_[4] = {bv2.x, bv2.y, bv2.z, bv2.w};
                #pragma unroll
                for (int i = 0; i < 4; ++i)
                    #pragma unroll
                    for (int j = 0; j < 4; ++j)
                        acc[i][j] += c_[i] * d_[j];
            }
        }
        __syncthreads();
    }

    #pragma unroll
    for (int i = 0; i < 4; ++i) {
        int row = row0 + (ty << 2) + i;
        const float* rt = nullptr;
        if (ROWBIAS) rt = &rowtab[(size_t)idx[row] * NO];
        float vv[4];
        #pragma unroll
        for (int j = 0; j < 4; ++j) {
            int col = col0 + (tx << 2) + j;
            float v = acc[i][j];
            if (bias) v += bias[col];
            if (ROWBIAS) v += rt[col];
            if (LEAKYACT) v = leaky(v);
            vv[j] = v;
        }
        float4 o; o.x = vv[0]; o.y = vv[1]; o.z = vv[2]; o.w = vv[3];
        *(float4*)&C[(size_t)row * NO + col0 + (tx << 2)] = o;
    }
}

// ---------- per-segment column reduce, 16B/lane (sum or max) ----------
template<bool ISMAX>
__global__ __launch_bounds__(256) void seg_reduce8(const ushort* __restrict__ in,
        const int* __restrict__ starts, float* __restrict__ out)
{
    __shared__ float part[8][HDIM];
    const int b = blockIdx.x, tid = threadIdx.x;
    const int sub = tid & 31, r = tid >> 5;
    const int s = starts[b], e = starts[b + 1];
    float a[8];
    #pragma unroll
    for (int j = 0; j < 8; ++j) a[j] = ISMAX ? -INFINITY : 0.f;
    for (int i = s + r; i < e; i += 8) {
        uint4 v = *(const uint4*)&in[(size_t)i * HDIM + sub * 8];
        float f[8] = { bf2f((ushort)v.x), bf2f((ushort)(v.x >> 16)),
                       bf2f((ushort)v.y), bf2f((ushort)(v.y >> 16)),
                       bf2f((ushort)v.z), bf2f((ushort)(v.z >> 16)),
                       bf2f((ushort)v.w), bf2f((ushort)(v.w >> 16)) };
        #pragma unroll
        for (int j = 0; j < 8; ++j) a[j] = ISMAX ? fmaxf(a[j], f[j]) : (a[j] + f[j]);
    }
    #pragma unroll
    for (int j = 0; j < 8; ++j) part[r][sub * 8 + j] = a[j];
    __syncthreads();
    float res = part[0][tid];
    #pragma unroll
    for (int j = 1; j < 8; ++j) res = ISMAX ? fmaxf(res, part[j][tid]) : (res + part[j][tid]);
    out[(size_t)b * HDIM + tid] = res;
}

// ---------- scatter softmax; prealpha = p0+p1+bias (fused combine) ----------
__global__ __launch_bounds__(64) void seg_softmax_k(const float* __restrict__ p0,
        const float* __restrict__ p1, const float* __restrict__ ab2,
        const int* __restrict__ starts, float* __restrict__ alpha)
{
    int b = blockIdx.x, lane = threadIdx.x;
    int s = starts[b], e = starts[b + 1];
    float bb = ab2[0];
    float m = -INFINITY;
    for (int i = s + lane; i < e; i += 64) m = fmaxf(m, p0[i] + p1[i] + bb);
    #pragma unroll
    for (int off = 32; off; off >>= 1) m = fmaxf(m, __shfl_xor(m, off));
    float sum = 0.f;
    for (int i = s + lane; i < e; i += 64) sum += expf(p0[i] + p1[i] + bb - m);
    #pragma unroll
    for (int off = 32; off; off >>= 1) sum += __shfl_xor(sum, off);
    sum += 1e-6f;
    for (int i = s + lane; i < e; i += 64) alpha[i] = expf(p0[i] + p1[i] + bb - m) / sum;
}

// ---------- vector[b,:] = sum raw[i,:]*alpha[i], 16B/lane ----------
__global__ __launch_bounds__(256) void seg_wsum8(const ushort* __restrict__ raw,
        const float* __restrict__ alpha, const int* __restrict__ starts,
        float* __restrict__ vec)
{
    __shared__ float part[8][HDIM];
    const int b = blockIdx.x, tid = threadIdx.x;
    const int sub = tid & 31, r = tid >> 5;
    const int s = starts[b], e = starts[b + 1];
    float a[8] = {};
    for (int i = s + r; i < e; i += 8) {
        float al = alpha[i];
        uint4 v = *(const uint4*)&raw[(size_t)i * HDIM + sub * 8];
        a[0] += bf2f((ushort)v.x) * al;        a[1] += bf2f((ushort)(v.x >> 16)) * al;
        a[2] += bf2f((ushort)v.y) * al;        a[3] += bf2f((ushort)(v.y >> 16)) * al;
        a[4] += bf2f((ushort)v.z) * al;        a[5] += bf2f((ushort)(v.z >> 16)) * al;
        a[6] += bf2f((ushort)v.w) * al;        a[7] += bf2f((ushort)(v.w >> 16)) * al;
    }
    #pragma unroll
    for (int j = 0; j < 8; ++j) part[r][sub * 8 + j] = a[j];
    __syncthreads();
    float res = 0.f;
    #pragma unroll
    for (int j = 0; j < 8; ++j) res += part[j][tid];
    vec[(size_t)b * HDIM + tid] = res;
}

// ---------- affinity head ----------
__global__ __launch_bounds__(256) void affinity_k(const float* __restrict__ vec,
        const float* __restrict__ W1, const float* __restrict__ b1,
        const float* __restrict__ W2, const float* __restrict__ b2,
        float* __restrict__ out)
{
    __shared__ float v[HDIM];
    __shared__ float red[4];
    int b = blockIdx.x, t = threadIdx.x;
    v[t] = vec[(size_t)b * HDIM + t];
    __syncthreads();
    float h = 0.f;
    #pragma unroll 8
    for (int k = 0; k < HDIM; ++k) h += v[k] * W1[(size_t)k * HDIM + t];
    h += b1[t];
    h = leaky(h);
    float p = h * W2[t];
    #pragma unroll
    for (int off = 32; off; off >>= 1) p += __shfl_down(p, off);
    int lane = t & 63, wid = t >> 6;
    if (lane == 0) red[wid] = p;
    __syncthreads();
    if (t == 0) out[b] = red[0] + red[1] + red[2] + red[3] + b2[0];
}

extern "C" void kernel_launch(void* const* d_in, const int* in_sizes, int n_in,
                              void* d_out, int out_size, void* d_ws, size_t ws_size,
                              hipStream_t stream)
{
    const int N = in_sizes[2];
    const int H = HDIM;
    const int B = BSEG;

    const float* comp   = (const float*)d_in[0];
    const float* prot   = (const float*)d_in[1];
    const int*   bc     = (const int*)d_in[2];
    const int*   bp     = (const int*)d_in[3];
    const float* c_aff_W = (const float*)d_in[4];
    const float* c_aff_b = (const float*)d_in[5];
    const float* c_sup_W = (const float*)d_in[6];
    const float* c_sup_b = (const float*)d_in[7];
    const float* p_aff_W = (const float*)d_in[8];
    const float* p_aff_b = (const float*)d_in[9];
    const float* raw_W1  = (const float*)d_in[10];
    const float* raw_b1  = (const float*)d_in[11];
    const float* raw_W2  = (const float*)d_in[12];
    const float* raw_b2  = (const float*)d_in[13];
    const float* alpha_W1 = (const float*)d_in[14];
    const float* alpha_b1 = (const float*)d_in[15];
    const float* alpha_W2 = (const float*)d_in[16];
    const float* alpha_b2 = (const float*)d_in[17];
    const float* out_W1  = (const float*)d_in[18];
    const float* out_b1  = (const float*)d_in[19];
    const float* out_W2  = (const float*)d_in[20];
    const float* out_b2  = (const float*)d_in[21];

    const size_t NBIG = (size_t)N * H;
    const size_t SSEG = (size_t)B * H;

    char* p = (char*)d_ws;
    ushort* e1 = (ushort*)p; p += NBIG * 2;   // comp_emb bf16
    ushort* e2 = (ushort*)p; p += NBIG * 2;   // csup bf16 -> raw bf16
    ushort* e3 = (ushort*)p; p += NBIG * 2;   // prot_emb bf16 -> hid_raw
    float* supe = (float*)p;  p += SSEG * 4;
    float* pool = (float*)p;  p += SSEG * 4;
    float* gr   = (float*)p;  p += SSEG * 4;
    float* ga   = (float*)p;  p += SSEG * 4;
    float* ppart = (float*)p; p += (size_t)2 * N * 4;      // alpha partial dots
    ushort* WT1 = (ushort*)p; p += (size_t)512 * 256 * 2;  // [c_aff^T ; c_sup^T]
    ushort* WTp = (ushort*)p; p += (size_t)256 * 256 * 2;  // p_aff^T
    ushort* WT2 = (ushort*)p; p += (size_t)512 * 256 * 2;  // [raw_W1[0:256]^T ; alpha_W1[0:256]^T]
    ushort* WTr = (ushort*)p; p += (size_t)256 * 256 * 2;  // raw_W2^T
    int* sc = (int*)p; p += (size_t)(B + 1) * 4;
    int* sp = (int*)p; p += (size_t)(B + 1) * 4;
    if ((size_t)(p - (char*)d_ws) > ws_size) return;

    ushort* h1   = e3;   // hid_raw (e3 dead after pool)
    ushort* rawb = e2;   // raw (e2 dead after supe)

    float* out_vec   = (float*)d_out;
    float* out_alpha = out_vec + SSEG;
    float* out_aff   = out_alpha + N;

    dim3 blk(256);

    seg_bounds_k<<<(2 * (B + 1) + 255) / 256, blk, 0, stream>>>(bc, bp, sc, sp, N, B);
    wt_cast_all<<<6 * 256, blk, 0, stream>>>(
        c_aff_W, c_sup_W, p_aff_W, raw_W1, alpha_W1, raw_W2,
        WT1, WT1 + 65536, WTp, WT2, WT2 + 65536, WTr);

    // G1: comp_emb | csup = leaky(comp @ [c_aff|c_sup] + bias)   (fp32 A stream)
    mgemm_w<true, false, true, false, 4><<<dim3(N / 128 * 4), blk, 0, stream>>>(
        comp, WT1, c_aff_b, c_sup_b, nullptr, nullptr, nullptr, e1, e2,
        nullptr, nullptr, N);
    // G2: prot_emb = leaky(prot @ p_aff + b)
    mgemm_w<true, false, true, false, 2><<<dim3(N / 128 * 2), blk, 0, stream>>>(
        prot, WTp, p_aff_b, nullptr, nullptr, nullptr, nullptr, e3, nullptr,
        nullptr, nullptr, N);
    // pools
    seg_reduce8<false><<<B, blk, 0, stream>>>(e2, sc, supe);
    seg_reduce8<true ><<<B, blk, 0, stream>>>(e3, sp, pool);
    // G-sums (bias folded here)
    gemm64<false, false, true><<<dim3(B / 64, 4), blk, 0, stream>>>(supe, raw_W1 + H * H, pool,
        raw_W1 + 2 * H * H, raw_b1, nullptr, nullptr, gr, B);
    gemm64<false, false, true><<<dim3(B / 64, 4), blk, 0, stream>>>(supe, alpha_W1 + H * H, pool,
        alpha_W1 + 2 * H * H, alpha_b1, nullptr, nullptr, ga, B);
    // G3: h1 = leaky(e1@W1r + gr[bc]);  alpha-half fused-dotted into ppart
    mgemm_w<true, true, false, true, 4><<<dim3(N / 128 * 4), blk, 0, stream>>>(
        e1, WT2, nullptr, nullptr, gr, ga, bc, h1, nullptr,
        alpha_W2, ppart, N);
    // softmax (combines ppart halves + bias)
    seg_softmax_k<<<B, dim3(64), 0, stream>>>(ppart, ppart + N, alpha_b2, sc, out_alpha);
    // G4: raw = h1 @ raw_W2 + b2
    mgemm_w<false, false, false, false, 2><<<dim3(N / 128 * 2), blk, 0, stream>>>(
        h1, WTr, raw_b2, nullptr, nullptr, nullptr, nullptr, rawb, nullptr,
        nullptr, nullptr, N);
    // vector
    seg_wsum8<<<B, blk, 0, stream>>>(rawb, out_alpha, sc, out_vec);
    // affinity
    affinity_k<<<B, blk, 0, stream>>>(out_vec, out_W1, out_b1, out_W2, out_b2, out_aff);
}

// Round 6
// 755.096 us; speedup vs baseline: 1.6274x; 1.6274x over previous
//
#include <hip/hip_runtime.h>
#include <cstddef>
#include <cstdint>

#define HDIM 256
#define BSEG 4096

typedef __bf16 bf16x8 __attribute__((ext_vector_type(8)));
typedef float f32x4 __attribute__((ext_vector_type(4)));

__device__ __forceinline__ float leaky(float x) { return x >= 0.f ? x : 0.1f * x; }
__device__ __forceinline__ float bf2f(ushort u) {
    return __builtin_bit_cast(float, (uint32_t)u << 16);
}
__device__ __forceinline__ ushort f2bf(float f) {  // RNE
    uint32_t x = __builtin_bit_cast(uint32_t, f);
    return (ushort)((x + 0x7fffu + ((x >> 16) & 1u)) >> 16);
}
__device__ __forceinline__ bf16x8 pack8(float4 a, float4 b) {
    union { ushort s[8]; bf16x8 v; } u;
    u.s[0] = f2bf(a.x); u.s[1] = f2bf(a.y); u.s[2] = f2bf(a.z); u.s[3] = f2bf(a.w);
    u.s[4] = f2bf(b.x); u.s[5] = f2bf(b.y); u.s[6] = f2bf(b.z); u.s[7] = f2bf(b.w);
    return u.v;
}
__device__ __forceinline__ void store_bf4(ushort* p, float v0, float v1, float v2, float v3) {
    ushort4 o; o.x = f2bf(v0); o.y = f2bf(v1); o.z = f2bf(v2); o.w = f2bf(v3);
    *(ushort4*)p = o;
}

__device__ __forceinline__ void gld16(const ushort* g, ushort* lds) {
    __builtin_amdgcn_global_load_lds(
        (const __attribute__((address_space(1))) uint32_t*)g,
        (__attribute__((address_space(3))) uint32_t*)lds, 16, 0, 0);
}
__device__ __forceinline__ void gld16f(const float* g, float* lds) {
    __builtin_amdgcn_global_load_lds(
        (const __attribute__((address_space(1))) uint32_t*)g,
        (__attribute__((address_space(3))) uint32_t*)lds, 16, 0, 0);
}

// ---------- segment bounds (batch arrays sorted) ----------
__global__ void seg_bounds_k(const int* __restrict__ bc, const int* __restrict__ bp,
                             int* __restrict__ sc, int* __restrict__ sp, int n, int nb)
{
    int t = blockIdx.x * blockDim.x + threadIdx.x;
    if (t >= 2 * (nb + 1)) return;
    bool isc = (t <= nb);
    const int* a = isc ? bc : bp;
    int v = isc ? t : t - (nb + 1);
    int lo = 0, hi = n;
    while (lo < hi) { int mid = (lo + hi) >> 1; if (a[mid] < v) lo = mid + 1; else hi = mid; }
    if (isc) sc[t] = lo; else sp[t - (nb + 1)] = lo;
}

// ---------- 6x 256x256 weight transpose+cast, LDS-tiled ----------
__global__ __launch_bounds__(256) void wt_cast_all(
    const float* __restrict__ s0, const float* __restrict__ s1,
    const float* __restrict__ s2, const float* __restrict__ s3,
    const float* __restrict__ s4, const float* __restrict__ s5,
    ushort* __restrict__ d0, ushort* __restrict__ d1, ushort* __restrict__ d2,
    ushort* __restrict__ d3, ushort* __restrict__ d4, ushort* __restrict__ d5)
{
    int m = blockIdx.x >> 4, tile = blockIdx.x & 15;
    const float* s = m == 0 ? s0 : m == 1 ? s1 : m == 2 ? s2 : m == 3 ? s3 : m == 4 ? s4 : s5;
    ushort*      d = m == 0 ? d0 : m == 1 ? d1 : m == 2 ? d2 : m == 3 ? d3 : m == 4 ? d4 : d5;
    int r0 = (tile >> 2) * 64, c0 = (tile & 3) * 64;
    __shared__ ushort t[64][72];
    int cc = threadIdx.x & 63, rr = threadIdx.x >> 6;
    for (int r = rr; r < 64; r += 4) t[cc][r] = f2bf(s[(size_t)(r0 + r) * 256 + c0 + cc]);
    __syncthreads();
    for (int r = rr; r < 64; r += 4) d[(size_t)(c0 + r) * 256 + r0 + cc] = t[r][cc];
}

// ---------- bf16 MFMA GEMM: 128x256 tile, 8 waves, dbuf LDS, 1 barrier/K-step ----------
// A:[nrows,256] fp32 (AFP32) or bf16, row-major. WT:[YT*256,256] bf16 (pre-transposed).
// cb = swz%YT selects the 256-col output matrix (bias/rt/out set).
// ALPHADOT && cb==1: hidden = leaky(acc + rt1[idx[row]]); pre[row] = dot(hidden, w2).
template<bool LEAKYACT, bool ROWBIAS, bool AFP32, bool ALPHADOT, int YT>
__global__ __launch_bounds__(512) void mg2(
    const void* __restrict__ Av, const ushort* __restrict__ WT,
    const float* __restrict__ bias0, const float* __restrict__ bias1,
    const float* __restrict__ rt0, const float* __restrict__ rt1,
    const int* __restrict__ idx,
    ushort* __restrict__ out0, ushort* __restrict__ out1,
    const float* __restrict__ w2, float* __restrict__ pre)
{
    __shared__ __attribute__((aligned(16))) ushort Bs[2][256 * 32];
    __shared__ __attribute__((aligned(16))) char AsRaw[2][AFP32 ? 128 * 32 * 4 : 128 * 32 * 2];
    __shared__ float pb[128][4];

    const int tid = threadIdx.x;
    const int l = tid & 63, w = tid >> 6;

    const uint nwg = gridDim.x, orig = blockIdx.x;
    const uint swz = (orig & 7) * (nwg >> 3) + (orig >> 3);   // XCD-chunked
    const int bx = (int)(swz / YT), cb = (int)(swz % YT);
    const int row0 = bx * 128, colb = cb * 256;

    const float*  Af = (const float*)Av;
    const ushort* Ah = (const ushort*)Av;

    // --- staging descriptors (dest = wave-uniform base + lane*16B; source pre-swizzled) ---
    // B: 1024 slots of 16B (4 slots per 32-elem row), two gld16 per lane
    const int sB0 = w * 128 + l;
    const int rB0 = sB0 >> 2,        rB1 = (sB0 + 64) >> 2;
    const int qB0 = (sB0 & 3) ^ ((rB0 >> 1) & 3), qB1 = ((sB0 + 64) & 3) ^ ((rB1 >> 1) & 3);
    const ushort* srcB0 = WT + (size_t)(colb + rB0) * HDIM + qB0 * 8;
    const ushort* srcB1 = WT + (size_t)(colb + rB1) * HDIM + qB1 * 8;
    // A fp32: 1024 slots (8 per row); A bf16: 512 slots (4 per row)
    const int sA0 = w * 128 + l;
    const int rA0 = sA0 >> 3,        rA1 = (sA0 + 64) >> 3;
    const int qA0 = (sA0 & 7) ^ (rA0 & 7), qA1 = ((sA0 + 64) & 7) ^ (rA1 & 7);
    const float* fsrc0 = Af + (size_t)(row0 + rA0) * HDIM + qA0 * 4;
    const float* fsrc1 = Af + (size_t)(row0 + rA1) * HDIM + qA1 * 4;
    const int rH = tid >> 2, qH = (tid & 3) ^ ((rH >> 1) & 3);
    const ushort* hsrc = Ah + (size_t)(row0 + rH) * HDIM + qH * 8;

    const int wr = (w >> 2) * 64, wc = (w & 3) * 64;
    const int lr = l & 15, lt = l >> 4;

    f32x4 acc[4][4] = {};

#define STAGE(buf, k0) do { \
        gld16(srcB0 + (k0), &Bs[buf][sB0 * 8]); \
        gld16(srcB1 + (k0), &Bs[buf][(sB0 + 64) * 8]); \
        if (AFP32) { \
            gld16f(fsrc0 + (k0), &((float*)AsRaw[buf])[sA0 * 4]); \
            gld16f(fsrc1 + (k0), &((float*)AsRaw[buf])[(sA0 + 64) * 4]); \
        } else { \
            gld16(hsrc + (k0), &((ushort*)AsRaw[buf])[tid * 8]); \
        } \
    } while (0)

#define COMPUTE(buf) do { \
        bf16x8 af[4], bv[4]; \
        _Pragma("unroll") \
        for (int m = 0; m < 4; ++m) { \
            const int row = wr + m * 16 + lr; \
            if (AFP32) { \
                const float* Ab = (const float*)AsRaw[buf]; \
                const int q0 = (2 * lt) ^ (row & 7), q1 = (2 * lt + 1) ^ (row & 7); \
                float4 x = *(const float4*)&Ab[row * 32 + q0 * 4]; \
                float4 y = *(const float4*)&Ab[row * 32 + q1 * 4]; \
                af[m] = pack8(x, y); \
            } else { \
                const ushort* Ab = (const ushort*)AsRaw[buf]; \
                const int q = lt ^ ((row >> 1) & 3); \
                af[m] = *(const bf16x8*)&Ab[row * 32 + q * 8]; \
            } \
        } \
        _Pragma("unroll") \
        for (int n = 0; n < 4; ++n) { \
            const int brow = wc + n * 16 + lr; \
            const int q = lt ^ ((brow >> 1) & 3); \
            bv[n] = *(const bf16x8*)&Bs[buf][brow * 32 + q * 8]; \
        } \
        _Pragma("unroll") \
        for (int m = 0; m < 4; ++m) \
            _Pragma("unroll") \
            for (int n = 0; n < 4; ++n) \
                acc[m][n] = __builtin_amdgcn_mfma_f32_16x16x32_bf16(bv[n], af[m], acc[m][n], 0, 0, 0); \
    } while (0)

    STAGE(0, 0);
    __syncthreads();
    int cur = 0;
    #pragma unroll
    for (int t = 1; t < 8; ++t) {
        STAGE(cur ^ 1, t * 32);
        COMPUTE(cur);
        __syncthreads();
        cur ^= 1;
    }
    COMPUTE(cur);

#undef STAGE
#undef COMPUTE

    if (ALPHADOT && cb == 1) {
        #pragma unroll
        for (int m = 0; m < 4; ++m) {
            const int row = row0 + wr + m * 16 + lr;
            const float* rrow = rt1 + (size_t)idx[row] * HDIM;
            float p = 0.f;
            #pragma unroll
            for (int n = 0; n < 4; ++n) {
                const int c = wc + n * 16 + (lt << 2);
                float4 r4 = *(const float4*)&rrow[c];
                float4 w4 = *(const float4*)&w2[c];
                float v0 = acc[m][n][0] + r4.x, v1 = acc[m][n][1] + r4.y;
                float v2 = acc[m][n][2] + r4.z, v3 = acc[m][n][3] + r4.w;
                if (LEAKYACT) { v0 = leaky(v0); v1 = leaky(v1); v2 = leaky(v2); v3 = leaky(v3); }
                p += v0 * w4.x + v1 * w4.y + v2 * w4.z + v3 * w4.w;
            }
            p += __shfl_xor(p, 16);
            p += __shfl_xor(p, 32);
            if (lt == 0) pb[wr + m * 16 + lr][w & 3] = p;
        }
        __syncthreads();
        if (tid < 128) pre[row0 + tid] = pb[tid][0] + pb[tid][1] + pb[tid][2] + pb[tid][3];
    } else {
        const float* bias = (YT == 2 && cb == 1) ? bias1 : bias0;
        const float* rtab = (YT == 2 && cb == 1) ? rt1 : rt0;
        ushort* outp = (YT == 2 && cb == 1) ? out1 : out0;
        #pragma unroll
        for (int m = 0; m < 4; ++m) {
            const int row = row0 + wr + m * 16 + lr;
            const float* rrow = nullptr;
            if (ROWBIAS) rrow = rtab + (size_t)idx[row] * HDIM;
            #pragma unroll
            for (int n = 0; n < 4; ++n) {
                const int c = wc + n * 16 + (lt << 2);
                float v0 = acc[m][n][0], v1 = acc[m][n][1], v2 = acc[m][n][2], v3 = acc[m][n][3];
                if (bias) {
                    float4 b4 = *(const float4*)&bias[c];
                    v0 += b4.x; v1 += b4.y; v2 += b4.z; v3 += b4.w;
                }
                if (ROWBIAS) {
                    float4 r4 = *(const float4*)&rrow[c];
                    v0 += r4.x; v1 += r4.y; v2 += r4.z; v3 += r4.w;
                }
                if (LEAKYACT) { v0 = leaky(v0); v1 = leaky(v1); v2 = leaky(v2); v3 = leaky(v3); }
                store_bf4(&outp[(size_t)row * HDIM + c], v0, v1, v2, v3);
            }
        }
    }
}

// ---------- fp32 dual GEMM for gr/ga: z picks the weight/bias set ----------
__global__ __launch_bounds__(256) void gemm64_2(
    const float* __restrict__ A, const float* __restrict__ A2,
    const float* __restrict__ Wb_r, const float* __restrict__ Wc_r, const float* __restrict__ bias_r,
    const float* __restrict__ Wb_a, const float* __restrict__ Wc_a, const float* __restrict__ bias_a,
    float* __restrict__ Cr, float* __restrict__ Ca)
{
    const int K = HDIM, NO = HDIM;
    const float* W  = blockIdx.z ? Wb_a : Wb_r;
    const float* W2 = blockIdx.z ? Wc_a : Wc_r;
    const float* bias = blockIdx.z ? bias_a : bias_r;
    float* C = blockIdx.z ? Ca : Cr;

    __shared__ float As [16][68];
    __shared__ float Bs [16][68];
    __shared__ float As2[16][68];
    __shared__ float Bs2[16][68];

    const int tid = threadIdx.x;
    const int tx = tid & 15, ty = tid >> 4;
    const int row0 = blockIdx.x * 64, col0 = blockIdx.y * 64;

    const int lr = tid >> 2;
    const int lk = (tid & 3) << 2;
    const int bk = tid >> 4;
    const int bj = (tid & 15) << 2;

    float acc[4][4] = {};

    for (int k0 = 0; k0 < K; k0 += 16) {
        float4 a4 = *(const float4*)&A[(size_t)(row0 + lr) * K + k0 + lk];
        As[lk + 0][lr] = a4.x; As[lk + 1][lr] = a4.y;
        As[lk + 2][lr] = a4.z; As[lk + 3][lr] = a4.w;
        *(float4*)&Bs[bk][bj] = *(const float4*)&W[(size_t)(k0 + bk) * NO + col0 + bj];
        float4 c4 = *(const float4*)&A2[(size_t)(row0 + lr) * K + k0 + lk];
        As2[lk + 0][lr] = c4.x; As2[lk + 1][lr] = c4.y;
        As2[lk + 2][lr] = c4.z; As2[lk + 3][lr] = c4.w;
        *(float4*)&Bs2[bk][bj] = *(const float4*)&W2[(size_t)(k0 + bk) * NO + col0 + bj];
        __syncthreads();
        #pragma unroll
        for (int kk = 0; kk < 16; ++kk) {
            float4 av = *(const float4*)&As[kk][ty << 2];
            float4 bv = *(const float4*)&Bs[kk][tx << 2];
            float a_[4] = {av.x, av.y, av.z, av.w};
            float b_[4] = {bv.x, bv.y, bv.z, bv.w};
            #pragma unroll
            for (int i = 0; i < 4; ++i)
                #pragma unroll
                for (int j = 0; j < 4; ++j)
                    acc[i][j] += a_[i] * b_[j];
            float4 av2 = *(const float4*)&As2[kk][ty << 2];
            float4 bv2 = *(const float4*)&Bs2[kk][tx << 2];
            float c_[4] = {av2.x, av2.y, av2.z, av2.w};
            float d_[4] = {bv2.x, bv2.y, bv2.z, bv2.w};
            #pragma unroll
            for (int i = 0; i < 4; ++i)
                #pragma unroll
                for (int j = 0; j < 4; ++j)
                    acc[i][j] += c_[i] * d_[j];
        }
        __syncthreads();
    }

    #pragma unroll
    for (int i = 0; i < 4; ++i) {
        int row = row0 + (ty << 2) + i;
        float vv[4];
        #pragma unroll
        for (int j = 0; j < 4; ++j) {
            int col = col0 + (tx << 2) + j;
            vv[j] = acc[i][j] + bias[col];
        }
        float4 o; o.x = vv[0]; o.y = vv[1]; o.z = vv[2]; o.w = vv[3];
        *(float4*)&C[(size_t)row * NO + col0 + (tx << 2)] = o;
    }
}

// ---------- per-segment column reduce, 16B/lane (sum or max) ----------
template<bool ISMAX>
__global__ __launch_bounds__(256) void seg_reduce8(const ushort* __restrict__ in,
        const int* __restrict__ starts, float* __restrict__ out)
{
    __shared__ float part[8][HDIM];
    const int b = blockIdx.x, tid = threadIdx.x;
    const int sub = tid & 31, r = tid >> 5;
    const int s = starts[b], e = starts[b + 1];
    float a[8];
    #pragma unroll
    for (int j = 0; j < 8; ++j) a[j] = ISMAX ? -INFINITY : 0.f;
    for (int i = s + r; i < e; i += 8) {
        uint4 v = *(const uint4*)&in[(size_t)i * HDIM + sub * 8];
        float f[8] = { bf2f((ushort)v.x), bf2f((ushort)(v.x >> 16)),
                       bf2f((ushort)v.y), bf2f((ushort)(v.y >> 16)),
                       bf2f((ushort)v.z), bf2f((ushort)(v.z >> 16)),
                       bf2f((ushort)v.w), bf2f((ushort)(v.w >> 16)) };
        #pragma unroll
        for (int j = 0; j < 8; ++j) a[j] = ISMAX ? fmaxf(a[j], f[j]) : (a[j] + f[j]);
    }
    #pragma unroll
    for (int j = 0; j < 8; ++j) part[r][sub * 8 + j] = a[j];
    __syncthreads();
    float res = part[0][tid];
    #pragma unroll
    for (int j = 1; j < 8; ++j) res = ISMAX ? fmaxf(res, part[j][tid]) : (res + part[j][tid]);
    out[(size_t)b * HDIM + tid] = res;
}

// ---------- scatter softmax over contiguous segments (uniform bias cancels) ----------
__global__ __launch_bounds__(64) void seg_softmax_k(const float* __restrict__ pre,
        const int* __restrict__ starts, float* __restrict__ alpha)
{
    int b = blockIdx.x, lane = threadIdx.x;
    int s = starts[b], e = starts[b + 1];
    float m = -INFINITY;
    for (int i = s + lane; i < e; i += 64) m = fmaxf(m, pre[i]);
    #pragma unroll
    for (int off = 32; off; off >>= 1) m = fmaxf(m, __shfl_xor(m, off));
    float sum = 0.f;
    for (int i = s + lane; i < e; i += 64) sum += expf(pre[i] - m);
    #pragma unroll
    for (int off = 32; off; off >>= 1) sum += __shfl_xor(sum, off);
    sum += 1e-6f;
    for (int i = s + lane; i < e; i += 64) alpha[i] = expf(pre[i] - m) / sum;
}

// ---------- vector[b,:] = sum raw[i,:]*alpha[i], 16B/lane ----------
__global__ __launch_bounds__(256) void seg_wsum8(const ushort* __restrict__ raw,
        const float* __restrict__ alpha, const int* __restrict__ starts,
        float* __restrict__ vec)
{
    __shared__ float part[8][HDIM];
    const int b = blockIdx.x, tid = threadIdx.x;
    const int sub = tid & 31, r = tid >> 5;
    const int s = starts[b], e = starts[b + 1];
    float a[8] = {};
    for (int i = s + r; i < e; i += 8) {
        float al = alpha[i];
        uint4 v = *(const uint4*)&raw[(size_t)i * HDIM + sub * 8];
        a[0] += bf2f((ushort)v.x) * al;        a[1] += bf2f((ushort)(v.x >> 16)) * al;
        a[2] += bf2f((ushort)v.y) * al;        a[3] += bf2f((ushort)(v.y >> 16)) * al;
        a[4] += bf2f((ushort)v.z) * al;        a[5] += bf2f((ushort)(v.z >> 16)) * al;
        a[6] += bf2f((ushort)v.w) * al;        a[7] += bf2f((ushort)(v.w >> 16)) * al;
    }
    #pragma unroll
    for (int j = 0; j < 8; ++j) part[r][sub * 8 + j] = a[j];
    __syncthreads();
    float res = 0.f;
    #pragma unroll
    for (int j = 0; j < 8; ++j) res += part[j][tid];
    vec[(size_t)b * HDIM + tid] = res;
}

// ---------- affinity head ----------
__global__ __launch_bounds__(256) void affinity_k(const float* __restrict__ vec,
        const float* __restrict__ W1, const float* __restrict__ b1,
        const float* __restrict__ W2, const float* __restrict__ b2,
        float* __restrict__ out)
{
    __shared__ float v[HDIM];
    __shared__ float red[4];
    int b = blockIdx.x, t = threadIdx.x;
    v[t] = vec[(size_t)b * HDIM + t];
    __syncthreads();
    float h = 0.f;
    #pragma unroll 8
    for (int k = 0; k < HDIM; ++k) h += v[k] * W1[(size_t)k * HDIM + t];
    h += b1[t];
    h = leaky(h);
    float p = h * W2[t];
    #pragma unroll
    for (int off = 32; off; off >>= 1) p += __shfl_down(p, off);
    int lane = t & 63, wid = t >> 6;
    if (lane == 0) red[wid] = p;
    __syncthreads();
    if (t == 0) out[b] = red[0] + red[1] + red[2] + red[3] + b2[0];
}

extern "C" void kernel_launch(void* const* d_in, const int* in_sizes, int n_in,
                              void* d_out, int out_size, void* d_ws, size_t ws_size,
                              hipStream_t stream)
{
    const int N = in_sizes[2];
    const int H = HDIM;
    const int B = BSEG;

    const float* comp   = (const float*)d_in[0];
    const float* prot   = (const float*)d_in[1];
    const int*   bc     = (const int*)d_in[2];
    const int*   bp     = (const int*)d_in[3];
    const float* c_aff_W = (const float*)d_in[4];
    const float* c_aff_b = (const float*)d_in[5];
    const float* c_sup_W = (const float*)d_in[6];
    const float* c_sup_b = (const float*)d_in[7];
    const float* p_aff_W = (const float*)d_in[8];
    const float* p_aff_b = (const float*)d_in[9];
    const float* raw_W1  = (const float*)d_in[10];
    const float* raw_b1  = (const float*)d_in[11];
    const float* raw_W2  = (const float*)d_in[12];
    const float* raw_b2  = (const float*)d_in[13];
    const float* alpha_W1 = (const float*)d_in[14];
    const float* alpha_b1 = (const float*)d_in[15];
    const float* alpha_W2 = (const float*)d_in[16];
    const float* out_W1  = (const float*)d_in[18];
    const float* out_b1  = (const float*)d_in[19];
    const float* out_W2  = (const float*)d_in[20];
    const float* out_b2  = (const float*)d_in[21];

    const size_t NBIG = (size_t)N * H;
    const size_t SSEG = (size_t)B * H;

    char* p = (char*)d_ws;
    ushort* e1 = (ushort*)p; p += NBIG * 2;   // comp_emb bf16
    ushort* e2 = (ushort*)p; p += NBIG * 2;   // csup bf16 -> raw bf16
    ushort* e3 = (ushort*)p; p += NBIG * 2;   // prot_emb bf16 -> hid_raw
    float* supe = (float*)p;  p += SSEG * 4;
    float* pool = (float*)p;  p += SSEG * 4;
    float* gr   = (float*)p;  p += SSEG * 4;
    float* ga   = (float*)p;  p += SSEG * 4;
    float* pre  = (float*)p;  p += (size_t)N * 4;
    ushort* WT1 = (ushort*)p; p += (size_t)512 * 256 * 2;  // [c_aff^T ; c_sup^T]
    ushort* WTp = (ushort*)p; p += (size_t)256 * 256 * 2;  // p_aff^T
    ushort* WT2 = (ushort*)p; p += (size_t)512 * 256 * 2;  // [raw_W1[0:256]^T ; alpha_W1[0:256]^T]
    ushort* WTr = (ushort*)p; p += (size_t)256 * 256 * 2;  // raw_W2^T
    int* sc = (int*)p; p += (size_t)(B + 1) * 4;
    int* sp = (int*)p; p += (size_t)(B + 1) * 4;
    if ((size_t)(p - (char*)d_ws) > ws_size) return;

    ushort* h1   = e3;   // hid_raw (e3 dead after pool)
    ushort* rawb = e2;   // raw     (e2 dead after supe)

    float* out_vec   = (float*)d_out;
    float* out_alpha = out_vec + SSEG;
    float* out_aff   = out_alpha + N;

    dim3 blk(256), blk5(512);

    seg_bounds_k<<<(2 * (B + 1) + 255) / 256, blk, 0, stream>>>(bc, bp, sc, sp, N, B);
    wt_cast_all<<<6 * 16, blk, 0, stream>>>(
        c_aff_W, c_sup_W, p_aff_W, raw_W1, alpha_W1, raw_W2,
        WT1, WT1 + 65536, WTp, WT2, WT2 + 65536, WTr);

    // G1: [e1|e2] = leaky(comp @ [c_aff|c_sup] + bias)   fp32 A direct
    mg2<true, false, true, false, 2><<<dim3(N / 128 * 2), blk5, 0, stream>>>(
        comp, WT1, c_aff_b, c_sup_b, nullptr, nullptr, nullptr, e1, e2, nullptr, nullptr);
    // G2: e3 = leaky(prot @ p_aff + b)                   fp32 A direct
    mg2<true, false, true, false, 1><<<dim3(N / 128), blk5, 0, stream>>>(
        prot, WTp, p_aff_b, nullptr, nullptr, nullptr, nullptr, e3, nullptr, nullptr, nullptr);
    // pools
    seg_reduce8<false><<<B, blk, 0, stream>>>(e2, sc, supe);
    seg_reduce8<true ><<<B, blk, 0, stream>>>(e3, sp, pool);
    // gr/ga = supe@W1[256:512] + pool@W1[512:768] + b1  (one z-routed launch)
    gemm64_2<<<dim3(B / 64, 4, 2), blk, 0, stream>>>(supe, pool,
        raw_W1 + H * H, raw_W1 + 2 * H * H, raw_b1,
        alpha_W1 + H * H, alpha_W1 + 2 * H * H, alpha_b1, gr, ga);
    // G3: cb0: h1 = leaky(e1@W1r + gr[bc]);  cb1: alpha-dot -> pre
    mg2<true, true, false, true, 2><<<dim3(N / 128 * 2), blk5, 0, stream>>>(
        e1, WT2, nullptr, nullptr, gr, ga, bc, h1, nullptr, alpha_W2, pre);
    // softmax (alpha_b2 cancels exactly)
    seg_softmax_k<<<B, dim3(64), 0, stream>>>(pre, sc, out_alpha);
    // G4: raw = h1 @ raw_W2 + b2
    mg2<false, false, false, false, 1><<<dim3(N / 128), blk5, 0, stream>>>(
        h1, WTr, raw_b2, nullptr, nullptr, nullptr, nullptr, rawb, nullptr, nullptr, nullptr);
    // vector
    seg_wsum8<<<B, blk, 0, stream>>>(rawb, out_alpha, sc, out_vec);
    // affinity
    affinity_k<<<B, blk, 0, stream>>>(out_vec, out_W1, out_b1, out_W2, out_b2, out_aff);
}

// Round 7
// 686.311 us; speedup vs baseline: 1.7905x; 1.1002x over previous
//
#include <hip/hip_runtime.h>
#include <cstddef>
#include <cstdint>

#define HDIM 256
#define BSEG 4096

typedef __bf16 bf16x8 __attribute__((ext_vector_type(8)));
typedef float f32x4 __attribute__((ext_vector_type(4)));

__device__ __forceinline__ float leaky(float x) { return x >= 0.f ? x : 0.1f * x; }
__device__ __forceinline__ float bf2f(ushort u) {
    return __builtin_bit_cast(float, (uint32_t)u << 16);
}
__device__ __forceinline__ ushort f2bf(float f) {  // RNE
    uint32_t x = __builtin_bit_cast(uint32_t, f);
    return (ushort)((x + 0x7fffu + ((x >> 16) & 1u)) >> 16);
}
__device__ __forceinline__ bf16x8 pack8(float4 a, float4 b) {
    union { ushort s[8]; bf16x8 v; } u;
    u.s[0] = f2bf(a.x); u.s[1] = f2bf(a.y); u.s[2] = f2bf(a.z); u.s[3] = f2bf(a.w);
    u.s[4] = f2bf(b.x); u.s[5] = f2bf(b.y); u.s[6] = f2bf(b.z); u.s[7] = f2bf(b.w);
    return u.v;
}
__device__ __forceinline__ void store_bf4(ushort* p, float v0, float v1, float v2, float v3) {
    ushort4 o; o.x = f2bf(v0); o.y = f2bf(v1); o.z = f2bf(v2); o.w = f2bf(v3);
    *(ushort4*)p = o;
}

__device__ __forceinline__ void gld16(const ushort* g, ushort* lds) {
    __builtin_amdgcn_global_load_lds(
        (const __attribute__((address_space(1))) uint32_t*)g,
        (__attribute__((address_space(3))) uint32_t*)lds, 16, 0, 0);
}

// ---------- segment bounds (batch arrays sorted) ----------
__global__ void seg_bounds_k(const int* __restrict__ bc, const int* __restrict__ bp,
                             int* __restrict__ sc, int* __restrict__ sp, int n, int nb)
{
    int t = blockIdx.x * blockDim.x + threadIdx.x;
    if (t >= 2 * (nb + 1)) return;
    bool isc = (t <= nb);
    const int* a = isc ? bc : bp;
    int v = isc ? t : t - (nb + 1);
    int lo = 0, hi = n;
    while (lo < hi) { int mid = (lo + hi) >> 1; if (a[mid] < v) lo = mid + 1; else hi = mid; }
    if (isc) sc[t] = lo; else sp[t - (nb + 1)] = lo;
}

// ---------- 5x 256x256 weight transpose+cast, LDS-tiled ----------
__global__ __launch_bounds__(256) void wt_cast_all(
    const float* __restrict__ s0, const float* __restrict__ s1,
    const float* __restrict__ s2, const float* __restrict__ s3,
    const float* __restrict__ s4,
    ushort* __restrict__ d0, ushort* __restrict__ d1, ushort* __restrict__ d2,
    ushort* __restrict__ d3, ushort* __restrict__ d4)
{
    int m = blockIdx.x >> 4, tile = blockIdx.x & 15;
    const float* s = m == 0 ? s0 : m == 1 ? s1 : m == 2 ? s2 : m == 3 ? s3 : s4;
    ushort*      d = m == 0 ? d0 : m == 1 ? d1 : m == 2 ? d2 : m == 3 ? d3 : d4;
    int r0 = (tile >> 2) * 64, c0 = (tile & 3) * 64;
    __shared__ ushort t[64][72];
    int cc = threadIdx.x & 63, rr = threadIdx.x >> 6;
    for (int r = rr; r < 64; r += 4) t[cc][r] = f2bf(s[(size_t)(r0 + r) * 256 + c0 + cc]);
    __syncthreads();
    for (int r = rr; r < 64; r += 4) d[(size_t)(c0 + r) * 256 + r0 + cc] = t[r][cc];
}

// ---------- bf16 MFMA GEMM: 128x256 tile, 8 waves, dbuf LDS, 1 barrier/K-step ----------
// A:[nrows,256] fp32 (AFP32, reg-staged + cvt) or bf16 (gld16), LDS always bf16 [128][32].
// WT:[YT*256,256] bf16 pre-transposed. cb = swz%YT selects the output col-set.
// ALPHADOT && cb==1: hidden = leaky(acc + rt1[idx[row]]); pre[row] = dot(hidden, w2).
template<bool LEAKYACT, bool ROWBIAS, bool AFP32, bool ALPHADOT, int YT>
__global__ __launch_bounds__(512) void mg3(
    const void* __restrict__ Av, const ushort* __restrict__ WT,
    const float* __restrict__ bias0, const float* __restrict__ bias1,
    const float* __restrict__ rt0, const float* __restrict__ rt1,
    const int* __restrict__ idx,
    ushort* __restrict__ out0, ushort* __restrict__ out1,
    const float* __restrict__ w2, float* __restrict__ pre)
{
    __shared__ __attribute__((aligned(16))) ushort Bs[2][256 * 32];
    __shared__ __attribute__((aligned(16))) ushort As[2][128 * 32];
    __shared__ float pb[128][4];

    const int tid = threadIdx.x;
    const int l = tid & 63, w = tid >> 6;

    const uint nwg = gridDim.x, orig = blockIdx.x;
    const uint swz = (orig & 7) * (nwg >> 3) + (orig >> 3);   // XCD-chunked
    const int bx = (int)(swz / YT), cb = (int)(swz % YT);
    const int row0 = bx * 128, colb = cb * 256;

    const float*  Af = (const float*)Av;
    const ushort* Ah = (const ushort*)Av;

    // --- B staging: 1024 slots of 16B (4 per 32-elem row), source pre-swizzled ---
    const int sB0 = w * 128 + l;
    const int rB0 = sB0 >> 2,        rB1 = (sB0 + 64) >> 2;
    const int qB0 = (sB0 & 3) ^ ((rB0 >> 1) & 3), qB1 = ((sB0 + 64) & 3) ^ ((rB1 >> 1) & 3);
    const ushort* srcB0 = WT + (size_t)(colb + rB0) * HDIM + qB0 * 8;
    const ushort* srcB1 = WT + (size_t)(colb + rB1) * HDIM + qB1 * 8;
    // --- A staging: 512 slots (4 per row), slot (srow, sj) holds chunk sj^((srow>>1)&3) ---
    const int srow = tid >> 2, sj = tid & 3;
    const int lj = sj ^ ((srow >> 1) & 3);
    const float*  fsrcA = Af + (size_t)(row0 + srow) * HDIM + lj * 8;
    const ushort* hsrcA = Ah + (size_t)(row0 + srow) * HDIM + lj * 8;

    const int wr = (w >> 2) * 64, wc = (w & 3) * 64;
    const int lr = l & 15, lt = l >> 4;

    f32x4 acc[4][4] = {};

#define STAGE_B(buf, k0) do { \
        gld16(srcB0 + (k0), &Bs[buf][sB0 * 8]); \
        gld16(srcB1 + (k0), &Bs[buf][(sB0 + 64) * 8]); \
    } while (0)

#define COMPUTE(buf) do { \
        bf16x8 af[4], bv[4]; \
        _Pragma("unroll") \
        for (int m = 0; m < 4; ++m) { \
            const int row = wr + m * 16 + lr; \
            const int q = lt ^ ((row >> 1) & 3); \
            af[m] = *(const bf16x8*)&As[buf][row * 32 + q * 8]; \
        } \
        _Pragma("unroll") \
        for (int n = 0; n < 4; ++n) { \
            const int brow = wc + n * 16 + lr; \
            const int q = lt ^ ((brow >> 1) & 3); \
            bv[n] = *(const bf16x8*)&Bs[buf][brow * 32 + q * 8]; \
        } \
        _Pragma("unroll") \
        for (int m = 0; m < 4; ++m) \
            _Pragma("unroll") \
            for (int n = 0; n < 4; ++n) \
                acc[m][n] = __builtin_amdgcn_mfma_f32_16x16x32_bf16(bv[n], af[m], acc[m][n], 0, 0, 0); \
    } while (0)

    int cur = 0;
    if (AFP32) {
        float4 av0, av1;
        av0 = *(const float4*)(fsrcA + 0);
        av1 = *(const float4*)(fsrcA + 4);
        STAGE_B(0, 0);
        *(bf16x8*)&As[0][tid * 8] = pack8(av0, av1);
        __syncthreads();
        #pragma unroll
        for (int t = 1; t < 8; ++t) {
            av0 = *(const float4*)(fsrcA + t * 32);
            av1 = *(const float4*)(fsrcA + t * 32 + 4);
            STAGE_B(cur ^ 1, t * 32);
            COMPUTE(cur);
            *(bf16x8*)&As[cur ^ 1][tid * 8] = pack8(av0, av1);
            __syncthreads();
            cur ^= 1;
        }
        COMPUTE(cur);
    } else {
        STAGE_B(0, 0);
        gld16(hsrcA, &As[0][tid * 8]);
        __syncthreads();
        #pragma unroll
        for (int t = 1; t < 8; ++t) {
            STAGE_B(cur ^ 1, t * 32);
            gld16(hsrcA + t * 32, &As[cur ^ 1][tid * 8]);
            COMPUTE(cur);
            __syncthreads();
            cur ^= 1;
        }
        COMPUTE(cur);
    }

#undef STAGE_B
#undef COMPUTE

    if (ALPHADOT && cb == 1) {
        #pragma unroll
        for (int m = 0; m < 4; ++m) {
            const int row = row0 + wr + m * 16 + lr;
            const float* rrow = rt1 + (size_t)idx[row] * HDIM;
            float p = 0.f;
            #pragma unroll
            for (int n = 0; n < 4; ++n) {
                const int c = wc + n * 16 + (lt << 2);
                float4 r4 = *(const float4*)&rrow[c];
                float4 w4 = *(const float4*)&w2[c];
                float v0 = acc[m][n][0] + r4.x, v1 = acc[m][n][1] + r4.y;
                float v2 = acc[m][n][2] + r4.z, v3 = acc[m][n][3] + r4.w;
                if (LEAKYACT) { v0 = leaky(v0); v1 = leaky(v1); v2 = leaky(v2); v3 = leaky(v3); }
                p += v0 * w4.x + v1 * w4.y + v2 * w4.z + v3 * w4.w;
            }
            p += __shfl_xor(p, 16);
            p += __shfl_xor(p, 32);
            if (lt == 0) pb[wr + m * 16 + lr][w & 3] = p;
        }
        __syncthreads();
        if (tid < 128) pre[row0 + tid] = pb[tid][0] + pb[tid][1] + pb[tid][2] + pb[tid][3];
    } else {
        const float* bias = (YT == 2 && cb == 1) ? bias1 : bias0;
        const float* rtab = (YT == 2 && cb == 1) ? rt1 : rt0;
        ushort* outp = (YT == 2 && cb == 1) ? out1 : out0;
        #pragma unroll
        for (int m = 0; m < 4; ++m) {
            const int row = row0 + wr + m * 16 + lr;
            const float* rrow = nullptr;
            if (ROWBIAS) rrow = rtab + (size_t)idx[row] * HDIM;
            #pragma unroll
            for (int n = 0; n < 4; ++n) {
                const int c = wc + n * 16 + (lt << 2);
                float v0 = acc[m][n][0], v1 = acc[m][n][1], v2 = acc[m][n][2], v3 = acc[m][n][3];
                if (bias) {
                    float4 b4 = *(const float4*)&bias[c];
                    v0 += b4.x; v1 += b4.y; v2 += b4.z; v3 += b4.w;
                }
                if (ROWBIAS) {
                    float4 r4 = *(const float4*)&rrow[c];
                    v0 += r4.x; v1 += r4.y; v2 += r4.z; v3 += r4.w;
                }
                if (LEAKYACT) { v0 = leaky(v0); v1 = leaky(v1); v2 = leaky(v2); v3 = leaky(v3); }
                store_bf4(&outp[(size_t)row * HDIM + c], v0, v1, v2, v3);
            }
        }
    }
}

// ---------- fp32 dual GEMM for gr/ga: z picks the weight/bias set ----------
__global__ __launch_bounds__(256) void gemm64_2(
    const float* __restrict__ A, const float* __restrict__ A2,
    const float* __restrict__ Wb_r, const float* __restrict__ Wc_r, const float* __restrict__ bias_r,
    const float* __restrict__ Wb_a, const float* __restrict__ Wc_a, const float* __restrict__ bias_a,
    float* __restrict__ Cr, float* __restrict__ Ca)
{
    const int K = HDIM, NO = HDIM;
    const float* W  = blockIdx.z ? Wb_a : Wb_r;
    const float* W2 = blockIdx.z ? Wc_a : Wc_r;
    const float* bias = blockIdx.z ? bias_a : bias_r;
    float* C = blockIdx.z ? Ca : Cr;

    __shared__ float As [16][68];
    __shared__ float Bs [16][68];
    __shared__ float As2[16][68];
    __shared__ float Bs2[16][68];

    const int tid = threadIdx.x;
    const int tx = tid & 15, ty = tid >> 4;
    const int row0 = blockIdx.x * 64, col0 = blockIdx.y * 64;

    const int lr = tid >> 2;
    const int lk = (tid & 3) << 2;
    const int bk = tid >> 4;
    const int bj = (tid & 15) << 2;

    float acc[4][4] = {};

    for (int k0 = 0; k0 < K; k0 += 16) {
        float4 a4 = *(const float4*)&A[(size_t)(row0 + lr) * K + k0 + lk];
        As[lk + 0][lr] = a4.x; As[lk + 1][lr] = a4.y;
        As[lk + 2][lr] = a4.z; As[lk + 3][lr] = a4.w;
        *(float4*)&Bs[bk][bj] = *(const float4*)&W[(size_t)(k0 + bk) * NO + col0 + bj];
        float4 c4 = *(const float4*)&A2[(size_t)(row0 + lr) * K + k0 + lk];
        As2[lk + 0][lr] = c4.x; As2[lk + 1][lr] = c4.y;
        As2[lk + 2][lr] = c4.z; As2[lk + 3][lr] = c4.w;
        *(float4*)&Bs2[bk][bj] = *(const float4*)&W2[(size_t)(k0 + bk) * NO + col0 + bj];
        __syncthreads();
        #pragma unroll
        for (int kk = 0; kk < 16; ++kk) {
            float4 av = *(const float4*)&As[kk][ty << 2];
            float4 bv = *(const float4*)&Bs[kk][tx << 2];
            float a_[4] = {av.x, av.y, av.z, av.w};
            float b_[4] = {bv.x, bv.y, bv.z, bv.w};
            #pragma unroll
            for (int i = 0; i < 4; ++i)
                #pragma unroll
                for (int j = 0; j < 4; ++j)
                    acc[i][j] += a_[i] * b_[j];
            float4 av2 = *(const float4*)&As2[kk][ty << 2];
            float4 bv2 = *(const float4*)&Bs2[kk][tx << 2];
            float c_[4] = {av2.x, av2.y, av2.z, av2.w};
            float d_[4] = {bv2.x, bv2.y, bv2.z, bv2.w};
            #pragma unroll
            for (int i = 0; i < 4; ++i)
                #pragma unroll
                for (int j = 0; j < 4; ++j)
                    acc[i][j] += c_[i] * d_[j];
        }
        __syncthreads();
    }

    #pragma unroll
    for (int i = 0; i < 4; ++i) {
        int row = row0 + (ty << 2) + i;
        float vv[4];
        #pragma unroll
        for (int j = 0; j < 4; ++j) {
            int col = col0 + (tx << 2) + j;
            vv[j] = acc[i][j] + bias[col];
        }
        float4 o; o.x = vv[0]; o.y = vv[1]; o.z = vv[2]; o.w = vv[3];
        *(float4*)&C[(size_t)row * NO + col0 + (tx << 2)] = o;
    }
}

// ---------- per-segment column reduce, 16B/lane (sum or max) ----------
template<bool ISMAX>
__global__ __launch_bounds__(256) void seg_reduce8(const ushort* __restrict__ in,
        const int* __restrict__ starts, float* __restrict__ out)
{
    __shared__ float part[8][HDIM];
    const int b = blockIdx.x, tid = threadIdx.x;
    const int sub = tid & 31, r = tid >> 5;
    const int s = starts[b], e = starts[b + 1];
    float a[8];
    #pragma unroll
    for (int j = 0; j < 8; ++j) a[j] = ISMAX ? -INFINITY : 0.f;
    for (int i = s + r; i < e; i += 8) {
        uint4 v = *(const uint4*)&in[(size_t)i * HDIM + sub * 8];
        float f[8] = { bf2f((ushort)v.x), bf2f((ushort)(v.x >> 16)),
                       bf2f((ushort)v.y), bf2f((ushort)(v.y >> 16)),
                       bf2f((ushort)v.z), bf2f((ushort)(v.z >> 16)),
                       bf2f((ushort)v.w), bf2f((ushort)(v.w >> 16)) };
        #pragma unroll
        for (int j = 0; j < 8; ++j) a[j] = ISMAX ? fmaxf(a[j], f[j]) : (a[j] + f[j]);
    }
    #pragma unroll
    for (int j = 0; j < 8; ++j) part[r][sub * 8 + j] = a[j];
    __syncthreads();
    float res = part[0][tid];
    #pragma unroll
    for (int j = 1; j < 8; ++j) res = ISMAX ? fmaxf(res, part[j][tid]) : (res + part[j][tid]);
    out[(size_t)b * HDIM + tid] = res;
}

// ---------- scatter softmax; also emits sa[b] = sum(alpha) = S/(S+1e-6) ----------
__global__ __launch_bounds__(64) void seg_softmax_k(const float* __restrict__ pre,
        const int* __restrict__ starts, float* __restrict__ alpha, float* __restrict__ sa)
{
    int b = blockIdx.x, lane = threadIdx.x;
    int s = starts[b], e = starts[b + 1];
    float m = -INFINITY;
    for (int i = s + lane; i < e; i += 64) m = fmaxf(m, pre[i]);
    #pragma unroll
    for (int off = 32; off; off >>= 1) m = fmaxf(m, __shfl_xor(m, off));
    float S = 0.f;
    for (int i = s + lane; i < e; i += 64) S += expf(pre[i] - m);
    #pragma unroll
    for (int off = 32; off; off >>= 1) S += __shfl_xor(S, off);
    float denom = S + 1e-6f;
    if (lane == 0) sa[b] = S / denom;
    for (int i = s + lane; i < e; i += 64) alpha[i] = expf(pre[i] - m) / denom;
}

// ---------- hw[b,:] = sum h1[i,:]*alpha[i], 16B/lane ----------
__global__ __launch_bounds__(256) void seg_wsum8(const ushort* __restrict__ raw,
        const float* __restrict__ alpha, const int* __restrict__ starts,
        float* __restrict__ vec)
{
    __shared__ float part[8][HDIM];
    const int b = blockIdx.x, tid = threadIdx.x;
    const int sub = tid & 31, r = tid >> 5;
    const int s = starts[b], e = starts[b + 1];
    float a[8] = {};
    for (int i = s + r; i < e; i += 8) {
        float al = alpha[i];
        uint4 v = *(const uint4*)&raw[(size_t)i * HDIM + sub * 8];
        a[0] += bf2f((ushort)v.x) * al;        a[1] += bf2f((ushort)(v.x >> 16)) * al;
        a[2] += bf2f((ushort)v.y) * al;        a[3] += bf2f((ushort)(v.y >> 16)) * al;
        a[4] += bf2f((ushort)v.z) * al;        a[5] += bf2f((ushort)(v.z >> 16)) * al;
        a[6] += bf2f((ushort)v.w) * al;        a[7] += bf2f((ushort)(v.w >> 16)) * al;
    }
    #pragma unroll
    for (int j = 0; j < 8; ++j) part[r][sub * 8 + j] = a[j];
    __syncthreads();
    float res = 0.f;
    #pragma unroll
    for (int j = 0; j < 8; ++j) res += part[j][tid];
    vec[(size_t)b * HDIM + tid] = res;
}

// ---------- final: vector = hw@raw_W2 + raw_b2*sa; affinity head ----------
__global__ __launch_bounds__(256) void final_k(
    const float* __restrict__ hw, const float* __restrict__ sa,
    const float* __restrict__ W2r, const float* __restrict__ rb2,
    const float* __restrict__ oW1, const float* __restrict__ ob1,
    const float* __restrict__ oW2, const float* __restrict__ ob2,
    float* __restrict__ out_vec, float* __restrict__ out_aff)
{
    __shared__ float v[HDIM];
    __shared__ float vecs[HDIM];
    __shared__ float red[4];
    int b = blockIdx.x, t = threadIdx.x;
    v[t] = hw[(size_t)b * HDIM + t];
    __syncthreads();
    float a = rb2[t] * sa[b];
    #pragma unroll 8
    for (int k = 0; k < HDIM; ++k) a += v[k] * W2r[(size_t)k * HDIM + t];
    out_vec[(size_t)b * HDIM + t] = a;
    vecs[t] = a;
    __syncthreads();
    float h = ob1[t];
    #pragma unroll 8
    for (int k = 0; k < HDIM; ++k) h += vecs[k] * oW1[(size_t)k * HDIM + t];
    h = leaky(h);
    float p = h * oW2[t];
    #pragma unroll
    for (int off = 32; off; off >>= 1) p += __shfl_down(p, off);
    int lane = t & 63, wid = t >> 6;
    if (lane == 0) red[wid] = p;
    __syncthreads();
    if (t == 0) out_aff[b] = red[0] + red[1] + red[2] + red[3] + ob2[0];
}

extern "C" void kernel_launch(void* const* d_in, const int* in_sizes, int n_in,
                              void* d_out, int out_size, void* d_ws, size_t ws_size,
                              hipStream_t stream)
{
    const int N = in_sizes[2];
    const int H = HDIM;
    const int B = BSEG;

    const float* comp   = (const float*)d_in[0];
    const float* prot   = (const float*)d_in[1];
    const int*   bc     = (const int*)d_in[2];
    const int*   bp     = (const int*)d_in[3];
    const float* c_aff_W = (const float*)d_in[4];
    const float* c_aff_b = (const float*)d_in[5];
    const float* c_sup_W = (const float*)d_in[6];
    const float* c_sup_b = (const float*)d_in[7];
    const float* p_aff_W = (const float*)d_in[8];
    const float* p_aff_b = (const float*)d_in[9];
    const float* raw_W1  = (const float*)d_in[10];
    const float* raw_b1  = (const float*)d_in[11];
    const float* raw_W2  = (const float*)d_in[12];
    const float* raw_b2  = (const float*)d_in[13];
    const float* alpha_W1 = (const float*)d_in[14];
    const float* alpha_b1 = (const float*)d_in[15];
    const float* alpha_W2 = (const float*)d_in[16];
    const float* out_W1  = (const float*)d_in[18];
    const float* out_b1  = (const float*)d_in[19];
    const float* out_W2  = (const float*)d_in[20];
    const float* out_b2  = (const float*)d_in[21];

    const size_t NBIG = (size_t)N * H;
    const size_t SSEG = (size_t)B * H;

    char* p = (char*)d_ws;
    ushort* e1 = (ushort*)p; p += NBIG * 2;   // comp_emb bf16
    ushort* e2 = (ushort*)p; p += NBIG * 2;   // csup bf16
    ushort* e3 = (ushort*)p; p += NBIG * 2;   // prot_emb bf16 -> h1 (hid_raw)
    float* supe = (float*)p;  p += SSEG * 4;
    float* pool = (float*)p;  p += SSEG * 4;
    float* gr   = (float*)p;  p += SSEG * 4;
    float* ga   = (float*)p;  p += SSEG * 4;
    float* hw   = (float*)p;  p += SSEG * 4;  // weighted sum of h1
    float* sa   = (float*)p;  p += (size_t)B * 4;
    float* pre  = (float*)p;  p += (size_t)N * 4;
    ushort* WT1 = (ushort*)p; p += (size_t)512 * 256 * 2;  // [c_aff^T ; c_sup^T]
    ushort* WTp = (ushort*)p; p += (size_t)256 * 256 * 2;  // p_aff^T
    ushort* WT2 = (ushort*)p; p += (size_t)512 * 256 * 2;  // [raw_W1[0:256]^T ; alpha_W1[0:256]^T]
    int* sc = (int*)p; p += (size_t)(B + 1) * 4;
    int* sp = (int*)p; p += (size_t)(B + 1) * 4;
    if ((size_t)(p - (char*)d_ws) > ws_size) return;

    ushort* h1 = e3;   // hid_raw (e3 dead after pool)

    float* out_vec   = (float*)d_out;
    float* out_alpha = out_vec + SSEG;
    float* out_aff   = out_alpha + N;

    dim3 blk(256), blk5(512);

    seg_bounds_k<<<(2 * (B + 1) + 255) / 256, blk, 0, stream>>>(bc, bp, sc, sp, N, B);
    wt_cast_all<<<5 * 16, blk, 0, stream>>>(
        c_aff_W, c_sup_W, p_aff_W, raw_W1, alpha_W1,
        WT1, WT1 + 65536, WTp, WT2, WT2 + 65536);

    // G1: [e1|e2] = leaky(comp @ [c_aff|c_sup] + bias)   fp32 A reg-staged
    mg3<true, false, true, false, 2><<<dim3(N / 128 * 2), blk5, 0, stream>>>(
        comp, WT1, c_aff_b, c_sup_b, nullptr, nullptr, nullptr, e1, e2, nullptr, nullptr);
    // G2: e3 = leaky(prot @ p_aff + b)
    mg3<true, false, true, false, 1><<<dim3(N / 128), blk5, 0, stream>>>(
        prot, WTp, p_aff_b, nullptr, nullptr, nullptr, nullptr, e3, nullptr, nullptr, nullptr);
    // pools
    seg_reduce8<false><<<B, blk, 0, stream>>>(e2, sc, supe);
    seg_reduce8<true ><<<B, blk, 0, stream>>>(e3, sp, pool);
    // gr/ga = supe@W1[256:512] + pool@W1[512:768] + b1
    gemm64_2<<<dim3(B / 64, 4, 2), blk, 0, stream>>>(supe, pool,
        raw_W1 + H * H, raw_W1 + 2 * H * H, raw_b1,
        alpha_W1 + H * H, alpha_W1 + 2 * H * H, alpha_b1, gr, ga);
    // G3: cb0: h1 = leaky(e1@W1r + gr[bc]);  cb1: alpha-dot -> pre
    mg3<true, true, false, true, 2><<<dim3(N / 128 * 2), blk5, 0, stream>>>(
        e1, WT2, nullptr, nullptr, gr, ga, bc, h1, nullptr, alpha_W2, pre);
    // softmax -> alpha + sa  (alpha_b2 cancels exactly)
    seg_softmax_k<<<B, dim3(64), 0, stream>>>(pre, sc, out_alpha, sa);
    // hw = seg_wsum(alpha * h1)
    seg_wsum8<<<B, blk, 0, stream>>>(h1, out_alpha, sc, hw);
    // vector = hw @ raw_W2 + raw_b2*sa ; affinity head
    final_k<<<B, blk, 0, stream>>>(hw, sa, raw_W2, raw_b2,
        out_W1, out_b1, out_W2, out_b2, out_vec, out_aff);
}